// Round 3
// baseline (485.425 us; speedup 1.0000x reference)
//
#include <hip/hip_runtime.h>
#include <hip/hip_bf16.h>
#include <stdint.h>

#define N_NODES 100000
#define N_RELS  8
#define N_EDGES 150000
#define KCOLS   1152   // K = 8*128 relation cols + 128 self-loop cols
#define CAP_R   16     // per-(dst,rel) bucket capacity (avg deg 1.5, max ~13)

typedef short bf16x8 __attribute__((ext_vector_type(8)));
typedef float f32x4  __attribute__((ext_vector_type(4)));

__device__ __forceinline__ unsigned short f2b(float f) {
    union { float f; unsigned u; } v; v.f = f;
    unsigned r = v.u + 0x7FFF + ((v.u >> 16) & 1);   // RNE
    return (unsigned short)(r >> 16);
}
__device__ __forceinline__ float b2f(unsigned short h) {
    union { unsigned u; float f; } v; v.u = ((unsigned)h) << 16;
    return v.f;
}

// ---------------------------------------------------------------------------
// BT[n][k]: bf16 weight transpose. n = out col, k in [0,1152)
// k<1024: W[r=k>>7, kk=k&127, n];  k>=1024: Wself[k-1024, n]
// ---------------------------------------------------------------------------
__global__ void prep_w(const float* __restrict__ W, const float* __restrict__ Wself,
                       unsigned short* __restrict__ BT) {
    int flat = blockIdx.x * 256 + threadIdx.x;
    if (flat >= 128 * KCOLS) return;
    int n = flat / KCOLS, k = flat - n * KCOLS;
    float v;
    if (k < 1024) {
        int r = k >> 7, kk = k & 127;
        v = W[(r << 14) + (kk << 7) + n];
    } else {
        v = Wself[((k - 1024) << 7) + n];
    }
    BT[flat] = f2b(v);
}

// x (f32) -> xb (bf16), 8 elems/thread
__global__ void cast_x(const float* __restrict__ X, unsigned short* __restrict__ xb) {
    int t = blockIdx.x * 256 + threadIdx.x;
    if (t >= N_NODES * 16) return;
    const float4* p = (const float4*)(X + (size_t)t * 8);
    float4 a = p[0], b = p[1];
    unsigned short o[8] = { f2b(a.x), f2b(a.y), f2b(a.z), f2b(a.w),
                            f2b(b.x), f2b(b.y), f2b(b.z), f2b(b.w) };
    *(int4*)(xb + (size_t)t * 8) = *(const int4*)o;
}

// per-edge scatter into per-(dst,rel) bucket
__global__ void edge_build_r(const int* __restrict__ src, const int* __restrict__ dst,
                             int* __restrict__ cnt8, int* __restrict__ ebufR) {
    int e = blockIdx.x * 256 + threadIdx.x;
    int r = blockIdx.y;
    if (e >= N_EDGES) return;
    int s = src[r * N_EDGES + e];
    int d = dst[r * N_EDGES + e];
    int slot = atomicAdd(&cnt8[d * 8 + r], 1);
    if (slot < CAP_R) ebufR[((size_t)d * 8 + r) * CAP_R + slot] = s;
}

// ---------------------------------------------------------------------------
// out[N,128] f32 = relu( [Agg | xb][N,1152] @ BT^T + bias ), Agg built on the
// fly per K-chunk: A-tile[row][k] = inv_deg * sum_{edges} xb[src][k].
// 128x128 out tile/block, 4 waves 2x2. K-loop: 8 relation chunks + self chunk.
// ---------------------------------------------------------------------------
__global__ __launch_bounds__(256) void gemm_fused(
    const unsigned short* __restrict__ xb, const unsigned short* __restrict__ BT,
    const int* __restrict__ cnt8, const int* __restrict__ ebufR,
    const float* __restrict__ bias, float* __restrict__ out) {
    __shared__ short As[128 * 136];      // 34.0 KB
    __shared__ short Bs[128 * 136];      // 34.0 KB
    __shared__ int   RecS[128 * CAP_R];  //  8.0 KB  records, current relation
    __shared__ int   CntC[128];          //  0.5 KB  raw counts, current relation

    int t = threadIdx.x;
    int rowBase = blockIdx.x * 128;
    int w = t >> 6, lane = t & 63;
    int wr = w >> 1, wc = w & 1;
    int ml = lane & 15, quad = lane >> 4;
    int col2 = lane << 1;                // each lane owns k-cols [2l, 2l+1]

    f32x4 acc[4][4];
#pragma unroll
    for (int i = 0; i < 4; ++i)
#pragma unroll
        for (int j = 0; j < 4; ++j)
            acc[i][j] = (f32x4){0.f, 0.f, 0.f, 0.f};

    for (int kc = 0; kc < 9; ++kc) {
        // ---- stage phase: Bs (+RecS/CntC for relation chunks) ----
#pragma unroll
        for (int it = 0; it < 8; ++it) {
            int idx = t + it * 256;
            int n = idx >> 4, c = idx & 15;
            *(int4*)&Bs[n * 136 + c * 8] =
                *(const int4*)&BT[(size_t)n * KCOLS + (kc << 7) + c * 8];
        }
        if (kc < 8) {
#pragma unroll
            for (int it = 0; it < 2; ++it) {
                int idx = t + it * 256;           // 512 int4 units
                int row = idx >> 2, c4 = idx & 3;
                int d = rowBase + row;
                int4 v = make_int4(0, 0, 0, 0);
                if (d < N_NODES)
                    v = *(const int4*)&ebufR[((size_t)d * 8 + kc) * CAP_R + c4 * 4];
                *(int4*)&RecS[row * CAP_R + c4 * 4] = v;
            }
            if (t < 128) {
                int d = rowBase + t;
                CntC[t] = (d < N_NODES) ? cnt8[d * 8 + kc] : 0;
            }
        } else {
            // self-loop chunk: A = xb rows directly
#pragma unroll
            for (int it = 0; it < 8; ++it) {
                int idx = t + it * 256;
                int row = idx >> 4, c = idx & 15;
                int grow = rowBase + row;
                int4 v = make_int4(0, 0, 0, 0);
                if (grow < N_NODES)
                    v = *(const int4*)&xb[(size_t)grow * 128 + c * 8];
                *(int4*)&As[row * 136 + c * 8] = v;
            }
        }
        __syncthreads();

        // ---- A-build phase (relation chunks): 4-row interleaved gather ----
        if (kc < 8) {
#pragma unroll 1
            for (int i0 = 0; i0 < 8; ++i0) {
                int rbase = w * 32 + i0;          // rows rbase + q*8, q<4
                float ax[4], ay[4], inv[4];
                int kq[4];
                int kmax = 0;
#pragma unroll
                for (int q = 0; q < 4; ++q) {
                    ax[q] = 0.f; ay[q] = 0.f;
                    int kraw = CntC[rbase + q * 8];
                    inv[q] = 1.0f / (float)(kraw < 1 ? 1 : kraw);
                    int k = kraw > CAP_R ? CAP_R : kraw;
                    kq[q] = k;
                    kmax = k > kmax ? k : kmax;
                }
#pragma unroll 1
                for (int j = 0; j < kmax; ++j) {
                    unsigned y2[4];
#pragma unroll
                    for (int q = 0; q < 4; ++q) {
                        if (j < kq[q]) {
                            int s = RecS[(rbase + q * 8) * CAP_R + j];
                            y2[q] = *(const unsigned*)&xb[(size_t)s * 128 + col2];
                        }
                    }
#pragma unroll
                    for (int q = 0; q < 4; ++q) {
                        if (j < kq[q]) {
                            ax[q] += b2f((unsigned short)(y2[q] & 0xFFFF));
                            ay[q] += b2f((unsigned short)(y2[q] >> 16));
                        }
                    }
                }
#pragma unroll
                for (int q = 0; q < 4; ++q) {
                    unsigned short lo = f2b(ax[q] * inv[q]);
                    unsigned short hi = f2b(ay[q] * inv[q]);
                    unsigned pk = (unsigned)lo | ((unsigned)hi << 16);
                    *(unsigned*)&As[(rbase + q * 8) * 136 + col2] = pk;
                }
            }
            __syncthreads();
        }

        // ---- MFMA phase ----
#pragma unroll
        for (int kb = 0; kb < 4; ++kb) {
            int ko = kb * 32 + quad * 8;
            bf16x8 a[4], b[4];
#pragma unroll
            for (int i = 0; i < 4; ++i)
                a[i] = *(const bf16x8*)&As[(wr * 64 + i * 16 + ml) * 136 + ko];
#pragma unroll
            for (int j = 0; j < 4; ++j)
                b[j] = *(const bf16x8*)&Bs[(wc * 64 + j * 16 + ml) * 136 + ko];
#pragma unroll
            for (int i = 0; i < 4; ++i)
#pragma unroll
                for (int j = 0; j < 4; ++j)
                    acc[i][j] = __builtin_amdgcn_mfma_f32_16x16x32_bf16(a[i], b[j], acc[i][j], 0, 0, 0);
        }
        __syncthreads();
    }

    // ---- epilogue: + bias, relu, f32 store ----
#pragma unroll
    for (int i = 0; i < 4; ++i) {
#pragma unroll
        for (int j = 0; j < 4; ++j) {
            int col = wc * 64 + j * 16 + ml;
            float bv = bias[col];
#pragma unroll
            for (int rr = 0; rr < 4; ++rr) {
                int row = rowBase + wr * 64 + i * 16 + quad * 4 + rr;
                if (row < N_NODES) {
                    float v = acc[i][j][rr] + bv;
                    out[(size_t)row * 128 + col] = fmaxf(v, 0.f);
                }
            }
        }
    }
}

// ---------------------------------------------------------------------------
extern "C" void kernel_launch(void* const* d_in, const int* in_sizes, int n_in,
                              void* d_out, int out_size, void* d_ws, size_t ws_size,
                              hipStream_t stream) {
    const float* x     = (const float*)d_in[0];
    const float* W     = (const float*)d_in[1];
    const float* Wself = (const float*)d_in[2];
    const float* bias  = (const float*)d_in[3];
    const int*   src   = (const int*)d_in[4];
    const int*   dst   = (const int*)d_in[5];
    float* out = (float*)d_out;

    char* ws = (char*)d_ws;
    size_t off = 0;
    unsigned short* xb = (unsigned short*)(ws + off); off += (size_t)N_NODES * 128 * 2;          // 25.6 MB
    unsigned short* BT = (unsigned short*)(ws + off); off += (size_t)128 * KCOLS * 2;            // 0.3 MB
    int* cnt8  = (int*)(ws + off); off += (size_t)N_NODES * 8 * 4;                               // 3.2 MB
    int* ebufR = (int*)(ws + off); off += (size_t)N_NODES * 8 * CAP_R * 4;                       // 51.2 MB

    hipMemsetAsync(cnt8, 0, (size_t)N_NODES * 8 * 4, stream);

    prep_w<<<(128 * KCOLS + 255) / 256, 256, 0, stream>>>(W, Wself, BT);
    cast_x<<<(N_NODES * 16 + 255) / 256, 256, 0, stream>>>(x, xb);

    dim3 eg((N_EDGES + 255) / 256, N_RELS);
    edge_build_r<<<eg, 256, 0, stream>>>(src, dst, cnt8, ebufR);

    gemm_fused<<<(N_NODES + 127) / 128, 256, 0, stream>>>(xb, BT, cnt8, ebufR, bias, out);
}